// Round 6
// baseline (232.605 us; speedup 1.0000x reference)
//
#include <hip/hip_runtime.h>

#define B_    8
#define CIN   128
#define COUT  128
#define NX    8192
#define KMJ   32
#define MODES 256

typedef short bf16x8 __attribute__((ext_vector_type(8)));
typedef float f32x4  __attribute__((ext_vector_type(4)));

__device__ __forceinline__ float bf2f(unsigned short u) {
    union { unsigned int i; float f; } v; v.i = ((unsigned int)u) << 16; return v.f;
}
__device__ __forceinline__ unsigned short f2bf(float f) {
    union { float f; unsigned int i; } v; v.f = f;
    unsigned int x = v.i;
    return (unsigned short)((x + 0x7fffu + ((x >> 16) & 1u)) >> 16);
}
__device__ __forceinline__ bf16x8 cvt8(const float* __restrict__ p) {
    f32x4 a = *(const f32x4*)p;
    f32x4 b = *(const f32x4*)(p + 4);
    bf16x8 r;
    r[0] = (short)f2bf(a[0]); r[1] = (short)f2bf(a[1]);
    r[2] = (short)f2bf(a[2]); r[3] = (short)f2bf(a[3]);
    r[4] = (short)f2bf(b[0]); r[5] = (short)f2bf(b[1]);
    r[6] = (short)f2bf(b[2]); r[7] = (short)f2bf(b[3]);
    return r;
}
__device__ __forceinline__ ushort4 cvt4(f32x4 a) {
    ushort4 r;
    r.x = f2bf(a[0]); r.y = f2bf(a[1]); r.z = f2bf(a[2]); r.w = f2bf(a[3]);
    return r;
}

// ---------------------------------------------------------------------------
// K1: Wk[k][o][i] = sum_j D[j][k] * weights[i][o][j]   (bf16 out, [k][o*?]..)
// A = D^T (M=k), B = weights[[j],(o,i)] (N = o*128+i). Coalesced stores.
// ---------------------------------------------------------------------------
__global__ __launch_bounds__(256) void k1_wk(const float* __restrict__ W,
                                             const float* __restrict__ D,
                                             unsigned short* __restrict__ Wk) {
    int wave = threadIdx.x >> 6, lane = threadIdx.x & 63;
    int quad = lane >> 4, l16 = lane & 15;
    int gw  = blockIdx.x * 4 + wave;    // 0..1023 : 16-wide tile over oi
    int oi0 = gw * 16;
    int i0  = oi0 & 127, o0 = oi0 >> 7;
    bf16x8 bfrag = cvt8(W + ((size_t)(i0 + l16) * COUT + o0) * KMJ + quad * 8);
    for (int mt = 0; mt < 16; mt++) {
        int k0 = mt * 16;
        bf16x8 afrag;
#pragma unroll
        for (int jj = 0; jj < 8; jj++)
            afrag[jj] = (short)f2bf(D[(quad * 8 + jj) * MODES + k0 + l16]);
        f32x4 acc = {0.f, 0.f, 0.f, 0.f};
        acc = __builtin_amdgcn_mfma_f32_16x16x32_bf16(afrag, bfrag, acc, 0, 0, 0);
#pragma unroll
        for (int r = 0; r < 4; r++)
            Wk[(size_t)(k0 + quad * 4 + r) * (CIN * COUT) + oi0 + l16] = f2bf(acc[r]);
    }
}

// ---------------------------------------------------------------------------
// K2 v4: PART[b][nt][c][kt*64+kk] = sum_{n in nt-chunk} x[b][c][n]*wb[b][n][k]
// Round-5 counters: 1 block/CU -> device-wide load/compute phase alternation,
// ~50% memory duty cycle (Occ 17%, all pipes idle). Fix: 4x grid via kt-split.
// grid (32 nt, 4 kt, 8 b) = 1024 blocks, 256 thr (4 waves, 2c x 2k wave grid,
// wave tile 64c x 32k). 8 steps of 32 n. LDS 14.6 KB -> 4 blocks/CU.
// Same-nt kt-siblings are 32 apart in dispatch -> same XCD (i%8) -> X via L2.
// ---------------------------------------------------------------------------
__global__ __launch_bounds__(256) void k2_xhat(const float* __restrict__ X,
                                               const float* __restrict__ WB,
                                               unsigned short* __restrict__ PART) {
    __shared__ __align__(16) unsigned short Xs[128 * 40];   // [c][40], cols 0..31
    __shared__ __align__(16) unsigned short WBs[32 * 68];   // [n][68],  cols 0..63
    int nt = blockIdx.x, kt = blockIdx.y, b = blockIdx.z;
    int r0 = nt * 256;
    int t  = threadIdx.x;
    int wave = t >> 6, lane = t & 63;
    int wm = wave >> 1, wn = wave & 1;
    int quad = lane >> 4, l16 = lane & 15;

    const float* xb  = X  + (size_t)b * CIN * NX;
    const float* wbb = WB + (size_t)b * NX * MODES + kt * 64;

    int xn4 = t & 7,  xc  = t >> 3;   // X: 8 f32x4 per 32-n row; rows xc+32r
    int wk4 = t & 15, wn0 = t >> 4;   // WB: 16 f32x4 per 64-k row; rows wn0+16r

    f32x4 acc[4][2];
#pragma unroll
    for (int i = 0; i < 4; i++)
#pragma unroll
        for (int j = 0; j < 2; j++) acc[i][j] = (f32x4){0.f, 0.f, 0.f, 0.f};

    for (int s = 0; s < 8; s++) {
        int rs = r0 + s * 32;
        f32x4 xv[4], wv[2];
#pragma unroll
        for (int r = 0; r < 4; r++)
            xv[r] = *(const f32x4*)(xb + (size_t)(xc + 32 * r) * NX + rs + xn4 * 4);
#pragma unroll
        for (int r = 0; r < 2; r++)
            wv[r] = *(const f32x4*)(wbb + (size_t)(rs + wn0 + 16 * r) * MODES + wk4 * 4);

        __syncthreads();   // previous step's frag reads complete
#pragma unroll
        for (int r = 0; r < 4; r++)
            *(ushort4*)(Xs + (xc + 32 * r) * 40 + xn4 * 4) = cvt4(xv[r]);
#pragma unroll
        for (int r = 0; r < 2; r++)
            *(ushort4*)(WBs + (wn0 + 16 * r) * 68 + wk4 * 4) = cvt4(wv[r]);
        __syncthreads();   // staging visible

        bf16x8 af[4];
#pragma unroll
        for (int tm = 0; tm < 4; tm++)
            af[tm] = *(const bf16x8*)(Xs + (wm * 64 + tm * 16 + l16) * 40 + quad * 8);
        bf16x8 bfv[2];
#pragma unroll
        for (int tn = 0; tn < 2; tn++) {
            int km = wn * 32 + tn * 16 + l16;
#pragma unroll
            for (int jj = 0; jj < 8; jj++)
                bfv[tn][jj] = (short)WBs[(quad * 8 + jj) * 68 + km];
        }
#pragma unroll
        for (int tm = 0; tm < 4; tm++)
#pragma unroll
            for (int tn = 0; tn < 2; tn++)
                acc[tm][tn] = __builtin_amdgcn_mfma_f32_16x16x32_bf16(af[tm], bfv[tn], acc[tm][tn], 0, 0, 0);
    }

    unsigned short* pb = PART + ((size_t)b * 32 + nt) * (CIN * MODES) + kt * 64;
#pragma unroll
    for (int tm = 0; tm < 4; tm++) {
        int c = wm * 64 + tm * 16 + quad * 4;
#pragma unroll
        for (int tn = 0; tn < 2; tn++) {
            int km = wn * 32 + tn * 16 + l16;
#pragma unroll
            for (int r = 0; r < 4; r++)
                pb[(size_t)(c + r) * MODES + km] = f2bf(acc[tm][tn][r]);
        }
    }
}

// ---------------------------------------------------------------------------
// K2b: XH[b][c][k] = sum_nt PART[b][nt][c][k]   (fp32 out, coalesced)
// ---------------------------------------------------------------------------
__global__ __launch_bounds__(256) void k2b_red(const unsigned short* __restrict__ PART,
                                               float* __restrict__ XH) {
    int e0 = blockIdx.x * 1024 + threadIdx.x;
#pragma unroll
    for (int r = 0; r < 4; r++) {
        int e = e0 + r * 256;
        int b = e >> 15, rem = e & 32767;
        const unsigned short* p = PART + (size_t)b * 32 * (CIN * MODES) + rem;
        float acc = 0.f;
#pragma unroll
        for (int nt = 0; nt < 32; nt++) acc += bf2f(p[nt * (CIN * MODES)]);
        XH[e] = acc;
    }
}

// ---------------------------------------------------------------------------
// K3 v3: y_hat[b][o][k] = sum_i x_hat[b][i][k] * Wk[k][o][i]
// grid (256 k, 4 oc) = 1024 blocks, 256 thr = 32 o x 8 b. Wk rows contiguous
// (bf16x8, b-lanes broadcast); XH slice in LDS (8-bank broadcast reads).
// ---------------------------------------------------------------------------
__global__ __launch_bounds__(256) void k3_yhat(const float* __restrict__ XH,
                                               const unsigned short* __restrict__ Wk,
                                               unsigned short* __restrict__ YH) {
    __shared__ float xs[128][8];
    int k = blockIdx.x, oc = blockIdx.y;
    int t = threadIdx.x;
#pragma unroll
    for (int l = 0; l < 4; l++) {
        int e = l * 256 + t;                   // 0..1023
        int i = e >> 3, b = e & 7;
        xs[i][b] = XH[(size_t)b * (CIN * MODES) + (size_t)i * MODES + k];
    }
    __syncthreads();
    int o = oc * 32 + (t >> 3), b = t & 7;
    const unsigned short* wp = Wk + (size_t)k * (CIN * COUT) + (size_t)o * CIN;
    float acc = 0.f;
#pragma unroll 4
    for (int ii = 0; ii < 16; ii++) {
        bf16x8 wc = *(const bf16x8*)(wp + ii * 8);
#pragma unroll
        for (int jj = 0; jj < 8; jj++)
            acc += bf2f((unsigned short)wc[jj]) * xs[ii * 8 + jj][b];
    }
    YH[((size_t)b * COUT + o) * MODES + k] = f2bf(acc);
}

// ---------------------------------------------------------------------------
// K4 v3: y[b][c][n] = sum_k y_hat[b][c][k] * bases[b][n][k]
// grid (128 nt, 8 b) = 1024 blocks, 256 thr, tile 128c x 64n, 8 steps of 32 k.
// LDS 13.8 KB -> 4 blocks/CU. YH re-reads served by L2 (64 KB slice/b).
// ---------------------------------------------------------------------------
__global__ __launch_bounds__(256) void k4_y(const unsigned short* __restrict__ YH,
                                            const float* __restrict__ BA,
                                            float* __restrict__ Y) {
    __shared__ __align__(16) unsigned short As[128 * 36];  // [c][36], cols 0..31
    __shared__ __align__(16) unsigned short Bs[64 * 36];   // [n][36], cols 0..31
    int nt = blockIdx.x, b = blockIdx.y;
    int n0 = nt * 64;
    int t  = threadIdx.x;
    int wave = t >> 6, lane = t & 63;
    int wm = wave >> 1, wn = wave & 1;
    int quad = lane >> 4, l16 = lane & 15;

    const unsigned short* yhb = YH + (size_t)b * COUT * MODES;
    const float* bab = BA + (size_t)b * NX * MODES + (size_t)n0 * MODES;

    int E0  = t * 8;                  // A-tile: chunk p at p*2048 + E0
    int ar0 = E0 >> 5, akk = E0 & 31;
    int ar1 = (2048 + E0) >> 5;
    int bk4 = t & 7, bn = t >> 3;     // B-tile: 8 f32x4 per 32-k row; rows bn+32r

    f32x4 acc[4][2];
#pragma unroll
    for (int i = 0; i < 4; i++)
#pragma unroll
        for (int j = 0; j < 2; j++) acc[i][j] = (f32x4){0.f, 0.f, 0.f, 0.f};

    for (int step = 0; step < 8; step++) {
        int ks = step * 32;
        bf16x8 av0 = *(const bf16x8*)(yhb + (size_t)ar0 * MODES + ks + akk);
        bf16x8 av1 = *(const bf16x8*)(yhb + (size_t)ar1 * MODES + ks + akk);
        f32x4 bv[2];
#pragma unroll
        for (int r = 0; r < 2; r++)
            bv[r] = *(const f32x4*)(bab + (size_t)(bn + 32 * r) * MODES + ks + bk4 * 4);

        __syncthreads();   // previous step's frag reads complete
        *(bf16x8*)(As + ar0 * 36 + akk) = av0;
        *(bf16x8*)(As + ar1 * 36 + akk) = av1;
#pragma unroll
        for (int r = 0; r < 2; r++)
            *(ushort4*)(Bs + (bn + 32 * r) * 36 + bk4 * 4) = cvt4(bv[r]);
        __syncthreads();   // staging visible

        bf16x8 af[4], bfv[2];
#pragma unroll
        for (int tm = 0; tm < 4; tm++)
            af[tm] = *(const bf16x8*)(As + (wm * 64 + tm * 16 + l16) * 36 + quad * 8);
#pragma unroll
        for (int tn = 0; tn < 2; tn++)
            bfv[tn] = *(const bf16x8*)(Bs + (wn * 32 + tn * 16 + l16) * 36 + quad * 8);
#pragma unroll
        for (int tm = 0; tm < 4; tm++)
#pragma unroll
            for (int tn = 0; tn < 2; tn++)
                acc[tm][tn] = __builtin_amdgcn_mfma_f32_16x16x32_bf16(af[tm], bfv[tn], acc[tm][tn], 0, 0, 0);
    }

    float* yb = Y + (size_t)b * COUT * NX;
#pragma unroll
    for (int tm = 0; tm < 4; tm++) {
        int o = wm * 64 + tm * 16 + quad * 4;
#pragma unroll
        for (int tn = 0; tn < 2; tn++) {
            int n = n0 + wn * 32 + tn * 16 + l16;
#pragma unroll
            for (int r = 0; r < 4; r++)
                yb[(size_t)(o + r) * NX + n] = acc[tm][tn][r];
        }
    }
}

extern "C" void kernel_launch(void* const* d_in, const int* in_sizes, int n_in,
                              void* d_out, int out_size, void* d_ws, size_t ws_size,
                              hipStream_t stream) {
    const float* X  = (const float*)d_in[0];  // [8][128][8192]
    const float* WB = (const float*)d_in[1];  // [8][8192][256]
    const float* BA = (const float*)d_in[2];  // [8][8192][256]
    const float* W  = (const float*)d_in[3];  // [128][128][32]
    const float* D  = (const float*)d_in[4];  // [32][256]
    float* Y = (float*)d_out;                 // [8][128][8192]

    char* ws = (char*)d_ws;
    unsigned short* Wk   = (unsigned short*)ws;                  // 8 MB bf16 [k][o][i]
    float*          XH   = (float*)(ws + (8u << 20));            // 1 MB fp32 [b][c][k]
    unsigned short* YH   = (unsigned short*)(ws + (9u << 20));   // 0.5 MB bf16 [b][o][k]
    unsigned short* PART = (unsigned short*)(ws + (10u << 20));  // 16.75 MB bf16 [b][nt][c][k]

    k1_wk  <<<256,             256, 0, stream>>>(W, D, Wk);
    k2_xhat<<<dim3(32, 4, 8),  256, 0, stream>>>(X, WB, PART);
    k2b_red<<<256,             256, 0, stream>>>(PART, XH);
    k3_yhat<<<dim3(256, 4),    256, 0, stream>>>(XH, Wk, YH);
    k4_y   <<<dim3(128, 8),    256, 0, stream>>>(YH, BA, Y);
}

// Round 7
// 228.522 us; speedup vs baseline: 1.0179x; 1.0179x over previous
//
#include <hip/hip_runtime.h>

#define B_    8
#define CIN   128
#define COUT  128
#define NX    8192
#define KMJ   32
#define MODES 256

typedef short bf16x8 __attribute__((ext_vector_type(8)));
typedef float f32x4  __attribute__((ext_vector_type(4)));

__device__ __forceinline__ float bf2f(unsigned short u) {
    union { unsigned int i; float f; } v; v.i = ((unsigned int)u) << 16; return v.f;
}
__device__ __forceinline__ unsigned short f2bf(float f) {
    union { float f; unsigned int i; } v; v.f = f;
    unsigned int x = v.i;
    return (unsigned short)((x + 0x7fffu + ((x >> 16) & 1u)) >> 16);
}
__device__ __forceinline__ bf16x8 cvt8(const float* __restrict__ p) {
    f32x4 a = *(const f32x4*)p;
    f32x4 b = *(const f32x4*)(p + 4);
    bf16x8 r;
    r[0] = (short)f2bf(a[0]); r[1] = (short)f2bf(a[1]);
    r[2] = (short)f2bf(a[2]); r[3] = (short)f2bf(a[3]);
    r[4] = (short)f2bf(b[0]); r[5] = (short)f2bf(b[1]);
    r[6] = (short)f2bf(b[2]); r[7] = (short)f2bf(b[3]);
    return r;
}
__device__ __forceinline__ ushort4 cvt4(f32x4 a) {
    ushort4 r;
    r.x = f2bf(a[0]); r.y = f2bf(a[1]); r.z = f2bf(a[2]); r.w = f2bf(a[3]);
    return r;
}

// ---------------------------------------------------------------------------
// K1 v3: Wk[k][o][i] = sum_j D[j][k] * weights[i][o][j]. grid (256, 4 mt-quads).
// ---------------------------------------------------------------------------
__global__ __launch_bounds__(256) void k1_wk(const float* __restrict__ W,
                                             const float* __restrict__ D,
                                             unsigned short* __restrict__ Wk) {
    int wave = threadIdx.x >> 6, lane = threadIdx.x & 63;
    int quad = lane >> 4, l16 = lane & 15;
    int gw  = blockIdx.x * 4 + wave;    // 0..1023 : 16-wide tile over oi
    int oi0 = gw * 16;
    int i0  = oi0 & 127, o0 = oi0 >> 7;
    bf16x8 bfrag = cvt8(W + ((size_t)(i0 + l16) * COUT + o0) * KMJ + quad * 8);
#pragma unroll
    for (int mtl = 0; mtl < 4; mtl++) {
        int k0 = (blockIdx.y * 4 + mtl) * 16;
        bf16x8 afrag;
#pragma unroll
        for (int jj = 0; jj < 8; jj++)
            afrag[jj] = (short)f2bf(D[(quad * 8 + jj) * MODES + k0 + l16]);
        f32x4 acc = {0.f, 0.f, 0.f, 0.f};
        acc = __builtin_amdgcn_mfma_f32_16x16x32_bf16(afrag, bfrag, acc, 0, 0, 0);
#pragma unroll
        for (int r = 0; r < 4; r++)
            Wk[(size_t)(k0 + quad * 4 + r) * (CIN * COUT) + oi0 + l16] = f2bf(acc[r]);
    }
}

// ---------------------------------------------------------------------------
// K2 v5: PART[b][nt][c][k] = sum_{n in 128-chunk} x[b][c][n]*wb[b][n][k]
// grid (64 nt, 8 b) = 512 blocks x 512 thr = 2 blocks/CU, 16 waves/CU.
// X and WB each read ONCE (100 MB total; r6's kt-split re-read X 4x for
// nothing). Double-buffered LDS -> ONE barrier/step. WB staged TRANSPOSED
// ([k][n+pad]) so B-frags are ds_read_b128, not 32 scalar u16 reads.
// 4 steps of 32 n. LDS 55 KB/block. launch_bounds caps VGPR at 128 for
// 2-block residency.
// ---------------------------------------------------------------------------
__global__ __launch_bounds__(512, 4) void k2_xhat(const float* __restrict__ X,
                                                  const float* __restrict__ WB,
                                                  unsigned short* __restrict__ PART) {
    __shared__ __align__(16) unsigned short Xs[2][128 * 40];   // [c][40], cols 0..31
    __shared__ __align__(16) unsigned short WBT[2][256 * 34];  // [k][34], cols 0..31 (n)
    int nt = blockIdx.x, b = blockIdx.y;
    int r0 = nt * 128;
    int t  = threadIdx.x;
    int wave = t >> 6, lane = t & 63;
    int wm = wave >> 2, wn = wave & 3;       // 2 c-halves x 4 k-quarters
    int quad = lane >> 4, l16 = lane & 15;

    const float* xb  = X  + (size_t)b * CIN * NX;
    const float* wbb = WB + (size_t)b * NX * MODES;

    int xn4 = t & 7,  xc  = t >> 3;   // X: 8 f32x4 per 32-n row; rows xc, xc+64
    int wk4 = t & 63, wn0 = t >> 6;   // WB: 64 f32x4 per 256-k row; n-rows wn0+8r

    f32x4 acc[4][4];
#pragma unroll
    for (int i = 0; i < 4; i++)
#pragma unroll
        for (int j = 0; j < 4; j++) acc[i][j] = (f32x4){0.f, 0.f, 0.f, 0.f};

    for (int s = 0; s < 4; s++) {
        int ns = r0 + s * 32;
        int bs = s & 1;
        f32x4 xv0 = *(const f32x4*)(xb + (size_t)xc * NX + ns + xn4 * 4);
        f32x4 xv1 = *(const f32x4*)(xb + (size_t)(xc + 64) * NX + ns + xn4 * 4);
        f32x4 wv[4];
#pragma unroll
        for (int r = 0; r < 4; r++)
            wv[r] = *(const f32x4*)(wbb + (size_t)(ns + wn0 + 8 * r) * MODES + wk4 * 4);

        *(ushort4*)(Xs[bs] + xc * 40 + xn4 * 4)        = cvt4(xv0);
        *(ushort4*)(Xs[bs] + (xc + 64) * 40 + xn4 * 4) = cvt4(xv1);
#pragma unroll
        for (int r = 0; r < 4; r++)
#pragma unroll
            for (int q = 0; q < 4; q++)
                WBT[bs][(wk4 * 4 + q) * 34 + wn0 + 8 * r] = f2bf(wv[r][q]);
        __syncthreads();   // single barrier per step (dbuf protects WAR)

        bf16x8 af[4];
#pragma unroll
        for (int tm = 0; tm < 4; tm++)
            af[tm] = *(const bf16x8*)(Xs[bs] + (wm * 64 + tm * 16 + l16) * 40 + quad * 8);
        bf16x8 bfv[4];
#pragma unroll
        for (int tn = 0; tn < 4; tn++)
            bfv[tn] = *(const bf16x8*)(WBT[bs] + (wn * 64 + tn * 16 + l16) * 34 + quad * 8);
#pragma unroll
        for (int tm = 0; tm < 4; tm++)
#pragma unroll
            for (int tn = 0; tn < 4; tn++)
                acc[tm][tn] = __builtin_amdgcn_mfma_f32_16x16x32_bf16(af[tm], bfv[tn], acc[tm][tn], 0, 0, 0);
    }

    unsigned short* pb = PART + ((size_t)b * 64 + nt) * (CIN * MODES);
#pragma unroll
    for (int tm = 0; tm < 4; tm++) {
        int c = wm * 64 + tm * 16 + quad * 4;
#pragma unroll
        for (int tn = 0; tn < 4; tn++) {
            int km = wn * 64 + tn * 16 + l16;
#pragma unroll
            for (int r = 0; r < 4; r++)
                pb[(size_t)(c + r) * MODES + km] = f2bf(acc[tm][tn][r]);
        }
    }
}

// ---------------------------------------------------------------------------
// K2b v2: XH[b][c][k] = sum_{nt<64} PART[b][nt][c][k]   (fp32 out)
// ---------------------------------------------------------------------------
__global__ __launch_bounds__(256) void k2b_red(const unsigned short* __restrict__ PART,
                                               float* __restrict__ XH) {
    int e0 = blockIdx.x * 512 + threadIdx.x;
#pragma unroll
    for (int r = 0; r < 2; r++) {
        int e = e0 + r * 256;                  // 0..262143
        int b = e >> 15, rem = e & 32767;
        const unsigned short* p = PART + (size_t)b * 64 * (CIN * MODES) + rem;
        float acc = 0.f;
#pragma unroll
        for (int nt = 0; nt < 64; nt++) acc += bf2f(p[nt * (CIN * MODES)]);
        XH[e] = acc;
    }
}

// ---------------------------------------------------------------------------
// K3 v4: y_hat[b][o][k] = sum_i x_hat[b][i][k] * Wk[k][o][i]
// grid (256 k, 4 oc) = 1024 blocks. 4-way split accumulators (break FMA chain).
// ---------------------------------------------------------------------------
__global__ __launch_bounds__(256) void k3_yhat(const float* __restrict__ XH,
                                               const unsigned short* __restrict__ Wk,
                                               unsigned short* __restrict__ YH) {
    __shared__ float xs[128][8];
    int k = blockIdx.x, oc = blockIdx.y;
    int t = threadIdx.x;
#pragma unroll
    for (int l = 0; l < 4; l++) {
        int e = l * 256 + t;                   // 0..1023
        int i = e >> 3, b = e & 7;
        xs[i][b] = XH[(size_t)b * (CIN * MODES) + (size_t)i * MODES + k];
    }
    __syncthreads();
    int o = oc * 32 + (t >> 3), b = t & 7;
    const unsigned short* wp = Wk + (size_t)k * (CIN * COUT) + (size_t)o * CIN;
    float a0 = 0.f, a1 = 0.f, a2 = 0.f, a3 = 0.f;
#pragma unroll
    for (int ii = 0; ii < 16; ii++) {
        bf16x8 wc = *(const bf16x8*)(wp + ii * 8);
        a0 += bf2f((unsigned short)wc[0]) * xs[ii * 8 + 0][b];
        a1 += bf2f((unsigned short)wc[1]) * xs[ii * 8 + 1][b];
        a2 += bf2f((unsigned short)wc[2]) * xs[ii * 8 + 2][b];
        a3 += bf2f((unsigned short)wc[3]) * xs[ii * 8 + 3][b];
        a0 += bf2f((unsigned short)wc[4]) * xs[ii * 8 + 4][b];
        a1 += bf2f((unsigned short)wc[5]) * xs[ii * 8 + 5][b];
        a2 += bf2f((unsigned short)wc[6]) * xs[ii * 8 + 6][b];
        a3 += bf2f((unsigned short)wc[7]) * xs[ii * 8 + 7][b];
    }
    YH[((size_t)b * COUT + o) * MODES + k] = f2bf((a0 + a1) + (a2 + a3));
}

// ---------------------------------------------------------------------------
// K4 v4: y[b][c][n] = sum_k y_hat[b][c][k] * bases[b][n][k]
// grid (64 nt, 8 b) = 512 blocks x 512 thr = 2 blocks/CU, 16 waves/CU.
// Tile 128c x 128n, 8 steps of 32 k. Double-buffered LDS (37 KB) -> one
// barrier/step; register prefetch of s+1 issued between barrier and MFMA.
// YH (0.5 MB) is L2-resident; HBM ~ BA 67 MB + Y 33.5 MB.
// ---------------------------------------------------------------------------
__global__ __launch_bounds__(512, 4) void k4_y(const unsigned short* __restrict__ YH,
                                               const float* __restrict__ BA,
                                               float* __restrict__ Y) {
    __shared__ __align__(16) unsigned short As[2][128 * 36];  // [c][36], cols 0..31
    __shared__ __align__(16) unsigned short Bs[2][128 * 36];  // [n][36], cols 0..31
    int nt = blockIdx.x, b = blockIdx.y;
    int n0 = nt * 128;
    int t  = threadIdx.x;
    int wave = t >> 6, lane = t & 63;
    int wm = wave >> 2, wn = wave & 3;       // 2 c-halves x 4 n-quarters (32 n)
    int quad = lane >> 4, l16 = lane & 15;

    const unsigned short* yhb = YH + (size_t)b * COUT * MODES;
    const float* bab = BA + (size_t)b * NX * MODES + (size_t)n0 * MODES;

    int ar  = t >> 2, akk = (t & 3) * 8;     // A: 1 bf16x8/thread over 128x32
    int bk4 = t & 7,  bn  = t >> 3;          // B: 8 f32x4 per 32-k row; rows bn, bn+64

    f32x4 acc[4][2];
#pragma unroll
    for (int i = 0; i < 4; i++)
#pragma unroll
        for (int j = 0; j < 2; j++) acc[i][j] = (f32x4){0.f, 0.f, 0.f, 0.f};

    // preload step 0
    bf16x8 av  = *(const bf16x8*)(yhb + (size_t)ar * MODES + akk);
    f32x4  bv0 = *(const f32x4*)(bab + (size_t)bn * MODES + bk4 * 4);
    f32x4  bv1 = *(const f32x4*)(bab + (size_t)(bn + 64) * MODES + bk4 * 4);

    for (int s = 0; s < 8; s++) {
        int bs = s & 1;
        *(bf16x8*)(As[bs] + ar * 36 + akk)          = av;
        *(ushort4*)(Bs[bs] + bn * 36 + bk4 * 4)        = cvt4(bv0);
        *(ushort4*)(Bs[bs] + (bn + 64) * 36 + bk4 * 4) = cvt4(bv1);
        __syncthreads();   // single barrier per step (dbuf protects WAR)

        if (s < 7) {       // prefetch s+1; drains behind the MFMAs below
            int ks = (s + 1) * 32;
            av  = *(const bf16x8*)(yhb + (size_t)ar * MODES + ks + akk);
            bv0 = *(const f32x4*)(bab + (size_t)bn * MODES + ks + bk4 * 4);
            bv1 = *(const f32x4*)(bab + (size_t)(bn + 64) * MODES + ks + bk4 * 4);
        }

        bf16x8 af[4], bfv[2];
#pragma unroll
        for (int tm = 0; tm < 4; tm++)
            af[tm] = *(const bf16x8*)(As[bs] + (wm * 64 + tm * 16 + l16) * 36 + quad * 8);
#pragma unroll
        for (int tn = 0; tn < 2; tn++)
            bfv[tn] = *(const bf16x8*)(Bs[bs] + (wn * 32 + tn * 16 + l16) * 36 + quad * 8);
#pragma unroll
        for (int tm = 0; tm < 4; tm++)
#pragma unroll
            for (int tn = 0; tn < 2; tn++)
                acc[tm][tn] = __builtin_amdgcn_mfma_f32_16x16x32_bf16(af[tm], bfv[tn], acc[tm][tn], 0, 0, 0);
    }

    float* yb = Y + (size_t)b * COUT * NX;
#pragma unroll
    for (int tm = 0; tm < 4; tm++) {
        int c = wm * 64 + tm * 16 + quad * 4;
#pragma unroll
        for (int tn = 0; tn < 2; tn++) {
            int n = n0 + wn * 32 + tn * 16 + l16;
#pragma unroll
            for (int r = 0; r < 4; r++)
                yb[(size_t)(c + r) * NX + n] = acc[tm][tn][r];
        }
    }
}

extern "C" void kernel_launch(void* const* d_in, const int* in_sizes, int n_in,
                              void* d_out, int out_size, void* d_ws, size_t ws_size,
                              hipStream_t stream) {
    const float* X  = (const float*)d_in[0];  // [8][128][8192]
    const float* WB = (const float*)d_in[1];  // [8][8192][256]
    const float* BA = (const float*)d_in[2];  // [8][8192][256]
    const float* W  = (const float*)d_in[3];  // [128][128][32]
    const float* D  = (const float*)d_in[4];  // [32][256]
    float* Y = (float*)d_out;                 // [8][128][8192]

    char* ws = (char*)d_ws;
    unsigned short* PART = (unsigned short*)ws;                  // 33.5 MB bf16 [b][64][c][k]
    unsigned short* Wk   = (unsigned short*)(ws + (34u << 20));  // 8 MB bf16 [k][o][i]
    float*          XH   = (float*)(ws + (42u << 20));           // 1 MB fp32 [b][c][k]
    unsigned short* YH   = (unsigned short*)(ws + (43u << 20));  // 0.5 MB bf16 [b][o][k]

    k1_wk  <<<dim3(256, 4),   256, 0, stream>>>(W, D, Wk);
    k2_xhat<<<dim3(64, 8),    512, 0, stream>>>(X, WB, PART);
    k2b_red<<<512,            256, 0, stream>>>(PART, XH);
    k3_yhat<<<dim3(256, 4),   256, 0, stream>>>(XH, Wk, YH);
    k4_y   <<<dim3(64, 8),    512, 0, stream>>>(YH, BA, Y);
}